// Round 2
// baseline (1466.814 us; speedup 1.0000x reference)
//
#include <hip/hip_runtime.h>
#include <math.h>

#define N_PAT 16384
#define D_DIM 16384
#define NB    256                 // blocks in fused pass (1 per CU, 1 round)
#define TPB   1024                // threads per block
#define ROWS  (N_PAT / NB)        // 64 rows per block
#define VPT   (D_DIM / (TPB * 4)) // 4 float4 per thread
#define NWAVE (TPB / 64)          // 16 waves
#define EPSV  1e-8f

// Load one row of P (64KB) into a register buffer: 4 float4 per thread.
#define LOADROW(buf, rr) do {                                              \
    const float4* __restrict__ pr_ = p0 + (size_t)(rr) * (D_DIM / 4);      \
    _Pragma("unroll")                                                      \
    for (int j_ = 0; j_ < VPT; ++j_) buf[j_] = pr_[TPB * j_];              \
} while (0)

// Per-row: dot/ssq block-reduce (raw barrier, lgkmcnt-only drain so prefetch
// loads stay in flight), sim, online-softmax update of register acc.
#define PROC(buf, slot) do {                                               \
    float dot_ = 0.f, ssq_ = 0.f;                                          \
    _Pragma("unroll")                                                      \
    for (int j_ = 0; j_ < VPT; ++j_) {                                     \
        dot_ = fmaf(buf[j_].x, xv[j_].x, dot_);                            \
        dot_ = fmaf(buf[j_].y, xv[j_].y, dot_);                            \
        dot_ = fmaf(buf[j_].z, xv[j_].z, dot_);                            \
        dot_ = fmaf(buf[j_].w, xv[j_].w, dot_);                            \
        ssq_ = fmaf(buf[j_].x, buf[j_].x, ssq_);                           \
        ssq_ = fmaf(buf[j_].y, buf[j_].y, ssq_);                           \
        ssq_ = fmaf(buf[j_].z, buf[j_].z, ssq_);                           \
        ssq_ = fmaf(buf[j_].w, buf[j_].w, ssq_);                           \
    }                                                                      \
    _Pragma("unroll")                                                      \
    for (int o_ = 32; o_ > 0; o_ >>= 1) {                                  \
        dot_ += __shfl_down(dot_, o_, 64);                                 \
        ssq_ += __shfl_down(ssq_, o_, 64);                                 \
    }                                                                      \
    if (lane == 0) {                                                       \
        volatile float2* rw_ = (volatile float2*)red[slot];                \
        rw_[wid].x = dot_; rw_[wid].y = ssq_;                              \
    }                                                                      \
    asm volatile("s_waitcnt lgkmcnt(0)" ::: "memory");                     \
    __builtin_amdgcn_s_barrier();                                          \
    asm volatile("" ::: "memory");                                         \
    dot_ = 0.f; ssq_ = 0.f;                                                \
    _Pragma("unroll")                                                      \
    for (int w_ = 0; w_ < NWAVE; ++w_) {                                   \
        volatile const float2* rr_ = (volatile const float2*)red[slot];    \
        float2 rv_; rv_.x = rr_[w_].x; rv_.y = rr_[w_].y;                  \
        dot_ += rv_.x; ssq_ += rv_.y;                                      \
    }                                                                      \
    const float s_ = dot_ * inv_xn / fmaxf(sqrtf(ssq_), EPSV);             \
    if (s_ > m) {                                                          \
        const float sc_ = __expf(m - s_);  /* exp(-inf)=0 first row */     \
        l = fmaf(l, sc_, 1.f);                                             \
        _Pragma("unroll")                                                  \
        for (int j_ = 0; j_ < VPT; ++j_) {                                 \
            acc[j_].x = fmaf(acc[j_].x, sc_, buf[j_].x);                   \
            acc[j_].y = fmaf(acc[j_].y, sc_, buf[j_].y);                   \
            acc[j_].z = fmaf(acc[j_].z, sc_, buf[j_].z);                   \
            acc[j_].w = fmaf(acc[j_].w, sc_, buf[j_].w);                   \
        }                                                                  \
        m = s_;                                                            \
    } else {                                                               \
        const float p_ = __expf(s_ - m);                                   \
        l += p_;                                                           \
        _Pragma("unroll")                                                  \
        for (int j_ = 0; j_ < VPT; ++j_) {                                 \
            acc[j_].x = fmaf(p_, buf[j_].x, acc[j_].x);                    \
            acc[j_].y = fmaf(p_, buf[j_].y, acc[j_].y);                    \
            acc[j_].z = fmaf(p_, buf[j_].z, acc[j_].z);                    \
            acc[j_].w = fmaf(p_, buf[j_].w, acc[j_].w);                    \
        }                                                                  \
    }                                                                      \
} while (0)

__global__ __launch_bounds__(TPB, 4) void fused_pass_kernel(
    const float* __restrict__ x, const float* __restrict__ P,
    float* __restrict__ accs, float* __restrict__ mlvals)
{
    __shared__ float2 red[2][NWAVE];   // parity slots -> 1 barrier per row
    const int t = threadIdx.x;
    const int b = blockIdx.x;
    const int lane = t & 63;
    const int wid = t >> 6;
    const float4* __restrict__ x4 = (const float4*)x;
    const float4* __restrict__ P4 = (const float4*)P;

    float4 xv[VPT], acc[VPT], va[VPT], vb[VPT];
    float xss = 0.f;
#pragma unroll
    for (int j = 0; j < VPT; ++j) {
        xv[j] = x4[t + TPB * j];
        acc[j] = make_float4(0.f, 0.f, 0.f, 0.f);
        xss += xv[j].x * xv[j].x + xv[j].y * xv[j].y
             + xv[j].z * xv[j].z + xv[j].w * xv[j].w;
    }
#pragma unroll
    for (int o = 32; o > 0; o >>= 1) xss += __shfl_down(xss, o, 64);
    if (lane == 0) { red[0][wid].x = xss; }
    __syncthreads();
    float xn = 0.f;
#pragma unroll
    for (int w = 0; w < NWAVE; ++w) xn += red[0][w].x;
    const float inv_xn = 1.f / fmaxf(sqrtf(xn), EPSV);
    __syncthreads();

    const float4* __restrict__ p0 =
        P4 + (size_t)b * ROWS * (D_DIM / 4) + t;

    float m = -INFINITY, l = 0.f;
    LOADROW(va, 0);
    for (int r = 0; r < ROWS; r += 2) {
        LOADROW(vb, r + 1);        // in flight across PROC(va)'s barrier
        PROC(va, 0);
        if (r + 2 < ROWS) LOADROW(va, r + 2);  // in flight across PROC(vb)
        PROC(vb, 1);
    }

    float4* __restrict__ oa = (float4*)(accs + (size_t)b * D_DIM);
#pragma unroll
    for (int j = 0; j < VPT; ++j) oa[t + TPB * j] = acc[j];
    if (t == 0) { mlvals[b] = m; mlvals[NB + b] = l; }
}

// Fused weights + combine: 1 wave per block (no barriers). Each block
// recomputes global M / denom from the 2*NB mlvals (cheap, L2-hot), builds
// w_b in LDS, then does out[d] = sum_b w_b * accs[b][d] for its 64 d's.
__global__ __launch_bounds__(64) void combine_kernel(
    const float* __restrict__ accs, const float* __restrict__ mlvals,
    float* __restrict__ out)
{
    const int lane = threadIdx.x;
    const int b = blockIdx.x;
    __shared__ float wsh[NB];

    float mv[NB / 64], lv[NB / 64];
#pragma unroll
    for (int k = 0; k < NB / 64; ++k) {
        mv[k] = mlvals[lane + 64 * k];
        lv[k] = mlvals[NB + lane + 64 * k];
    }
    float mm = mv[0];
#pragma unroll
    for (int k = 1; k < NB / 64; ++k) mm = fmaxf(mm, mv[k]);
#pragma unroll
    for (int o = 32; o > 0; o >>= 1) mm = fmaxf(mm, __shfl_down(mm, o, 64));
    mm = __shfl(mm, 0, 64);            // global max M
    float c = 0.f;
#pragma unroll
    for (int k = 0; k < NB / 64; ++k) c += lv[k] * __expf(mv[k] - mm);
#pragma unroll
    for (int o = 32; o > 0; o >>= 1) c += __shfl_down(c, o, 64);
    c = __shfl(c, 0, 64);              // softmax denom
    const float inv = 1.f / (c * (float)N_PAT);
#pragma unroll
    for (int k = 0; k < NB / 64; ++k)
        wsh[lane + 64 * k] = __expf(mv[k] - mm) * inv;
    __syncthreads();                   // single wave; orders LDS write->read

    const int d = b * 64 + lane;
    float s = 0.f;
#pragma unroll 8
    for (int bb = 0; bb < NB; ++bb)
        s = fmaf(wsh[bb], accs[(size_t)bb * D_DIM + d], s);
    out[d] = s;
}

extern "C" void kernel_launch(void* const* d_in, const int* in_sizes, int n_in,
                              void* d_out, int out_size, void* d_ws, size_t ws_size,
                              hipStream_t stream) {
    const float* x = (const float*)d_in[0];        // 128*128 f32
    const float* P = (const float*)d_in[1];        // 16384*16384 f32
    float* out = (float*)d_out;                    // 16384 f32

    float* accs   = (float*)d_ws;                  // NB * D floats = 16 MB
    float* mlvals = accs + (size_t)NB * D_DIM;     // 2*NB floats (m then l)

    fused_pass_kernel<<<NB, TPB, 0, stream>>>(x, P, accs, mlvals);
    combine_kernel<<<D_DIM / 64, 64, 0, stream>>>(accs, mlvals, out);
}

// Round 3
// 439.343 us; speedup vs baseline: 3.3387x; 3.3387x over previous
//
#include <hip/hip_runtime.h>
#include <math.h>

#define N_PAT 16384
#define D_DIM 16384
#define NB    512                 // fused-pass blocks: 2 per CU, all co-resident
#define TPB   512                 // 8 waves
#define ROWS  (N_PAT / NB)        // 32 rows per block
#define VPT   (D_DIM / (TPB * 4)) // 8 float4 per thread
#define NWAVE (TPB / 64)          // 8 waves
#define EPSV  1e-8f

// One fused pass: each block streams 32 rows of P exactly once. Per row:
// dot(P_n, x) and sumsq(P_n) via wave-shfl + one-barrier LDS block reduce,
// then online-softmax update of a register-resident weighted-sum partial.
// TLP (2 blocks/CU) hides the per-row reduce bubble; registers pinned to a
// 128-VGPR budget (4 waves/EU) so nothing spills (round-2 lesson: VGPR=64
// allocation spilled acc/row buffers -> 5.4 GB scratch traffic).
__global__ __launch_bounds__(TPB) __attribute__((amdgpu_waves_per_eu(4, 4)))
void fused_pass_kernel(
    const float* __restrict__ x, const float* __restrict__ P,
    float* __restrict__ accs, float* __restrict__ mlvals)
{
    __shared__ float2 red[2][NWAVE];   // parity slots -> 1 barrier per row
    const int t = threadIdx.x;
    const int b = blockIdx.x;
    const int lane = t & 63;
    const int wid = t >> 6;
    const float4* __restrict__ x4 = (const float4*)x;
    const float4* __restrict__ P4 = (const float4*)P;

    float4 xv[VPT], acc[VPT], v[VPT];
    float xss = 0.f;
#pragma unroll
    for (int j = 0; j < VPT; ++j) {
        xv[j] = x4[t + TPB * j];
        acc[j] = make_float4(0.f, 0.f, 0.f, 0.f);
        xss += xv[j].x * xv[j].x + xv[j].y * xv[j].y
             + xv[j].z * xv[j].z + xv[j].w * xv[j].w;
    }
#pragma unroll
    for (int o = 32; o > 0; o >>= 1) xss += __shfl_down(xss, o, 64);
    if (lane == 0) red[0][wid] = make_float2(xss, 0.f);
    __syncthreads();
    float xn = 0.f;
#pragma unroll
    for (int w = 0; w < NWAVE; ++w) xn += red[0][w].x;
    const float inv_xn = 1.f / fmaxf(sqrtf(xn), EPSV);
    __syncthreads();

    const float4* __restrict__ p0 = P4 + (size_t)b * ROWS * (D_DIM / 4) + t;

    float m = -INFINITY, l = 0.f;
    for (int r = 0; r < ROWS; ++r) {
        const float4* __restrict__ pr = p0 + (size_t)r * (D_DIM / 4);
#pragma unroll
        for (int j = 0; j < VPT; ++j) v[j] = pr[TPB * j];
        float dot = 0.f, ssq = 0.f;
#pragma unroll
        for (int j = 0; j < VPT; ++j) {
            dot = fmaf(v[j].x, xv[j].x, dot); dot = fmaf(v[j].y, xv[j].y, dot);
            dot = fmaf(v[j].z, xv[j].z, dot); dot = fmaf(v[j].w, xv[j].w, dot);
            ssq = fmaf(v[j].x, v[j].x, ssq);  ssq = fmaf(v[j].y, v[j].y, ssq);
            ssq = fmaf(v[j].z, v[j].z, ssq);  ssq = fmaf(v[j].w, v[j].w, ssq);
        }
#pragma unroll
        for (int o = 32; o > 0; o >>= 1) {
            dot += __shfl_down(dot, o, 64);
            ssq += __shfl_down(ssq, o, 64);
        }
        if (lane == 0) red[r & 1][wid] = make_float2(dot, ssq);
        __syncthreads();
        dot = 0.f; ssq = 0.f;
#pragma unroll
        for (int w = 0; w < NWAVE; ++w) {
            const float2 rv = red[r & 1][w];
            dot += rv.x; ssq += rv.y;
        }
        const float s = dot * inv_xn / fmaxf(sqrtf(ssq), EPSV);
        if (s > m) {                    // block-uniform branch
            const float sc = __expf(m - s);   // exp(-inf)=0 on first row
            l = fmaf(l, sc, 1.f);
#pragma unroll
            for (int j = 0; j < VPT; ++j) {
                acc[j].x = fmaf(acc[j].x, sc, v[j].x);
                acc[j].y = fmaf(acc[j].y, sc, v[j].y);
                acc[j].z = fmaf(acc[j].z, sc, v[j].z);
                acc[j].w = fmaf(acc[j].w, sc, v[j].w);
            }
            m = s;
        } else {
            const float p = __expf(s - m);
            l += p;
#pragma unroll
            for (int j = 0; j < VPT; ++j) {
                acc[j].x = fmaf(p, v[j].x, acc[j].x);
                acc[j].y = fmaf(p, v[j].y, acc[j].y);
                acc[j].z = fmaf(p, v[j].z, acc[j].z);
                acc[j].w = fmaf(p, v[j].w, acc[j].w);
            }
        }
    }

    float4* __restrict__ oa = (float4*)(accs + (size_t)b * D_DIM);
#pragma unroll
    for (int j = 0; j < VPT; ++j) oa[t + TPB * j] = acc[j];
    if (t == 0) { mlvals[b] = m; mlvals[NB + b] = l; }
}

// Combine: 256 blocks x 256 threads. Each block owns 64 output d's; its 4
// waves split the 512 per-block partials (128 each) for 4x the load ILP,
// then LDS tree-reduce. Weights recomputed per block from mlvals (L2-hot).
__global__ __launch_bounds__(256) void combine_kernel(
    const float* __restrict__ accs, const float* __restrict__ mlvals,
    float* __restrict__ out)
{
    __shared__ float wsh[NB];
    __shared__ float red2[4][64];
    __shared__ float mred[4], dred[4];
    const int t = threadIdx.x;
    const int lane = t & 63;
    const int w = t >> 6;

    // each thread loads 2 of the 512 (m,l) pairs
    const float m0 = mlvals[t],        m1 = mlvals[t + 256];
    const float l0 = mlvals[NB + t],   l1 = mlvals[NB + t + 256];
    float mm = fmaxf(m0, m1);
#pragma unroll
    for (int o = 32; o > 0; o >>= 1) mm = fmaxf(mm, __shfl_down(mm, o, 64));
    if (lane == 0) mred[w] = mm;
    __syncthreads();
    const float M = fmaxf(fmaxf(mred[0], mred[1]), fmaxf(mred[2], mred[3]));
    const float e0 = __expf(m0 - M), e1 = __expf(m1 - M);
    float c = l0 * e0 + l1 * e1;
#pragma unroll
    for (int o = 32; o > 0; o >>= 1) c += __shfl_down(c, o, 64);
    if (lane == 0) dred[w] = c;
    __syncthreads();
    const float denom = dred[0] + dred[1] + dred[2] + dred[3];
    const float inv = 1.f / (denom * (float)N_PAT);
    wsh[t] = e0 * inv;
    wsh[t + 256] = e1 * inv;
    __syncthreads();

    const int d = blockIdx.x * 64 + lane;
    float s = 0.f;
#pragma unroll 8
    for (int bb = w * (NB / 4); bb < (w + 1) * (NB / 4); ++bb)
        s = fmaf(wsh[bb], accs[(size_t)bb * D_DIM + d], s);
    red2[w][lane] = s;
    __syncthreads();
    if (w == 0)
        out[d] = red2[0][lane] + red2[1][lane] + red2[2][lane] + red2[3][lane];
}

extern "C" void kernel_launch(void* const* d_in, const int* in_sizes, int n_in,
                              void* d_out, int out_size, void* d_ws, size_t ws_size,
                              hipStream_t stream) {
    const float* x = (const float*)d_in[0];        // 128*128 f32
    const float* P = (const float*)d_in[1];        // 16384*16384 f32
    float* out = (float*)d_out;                    // 16384 f32

    float* accs   = (float*)d_ws;                  // NB * D floats = 32 MB
    float* mlvals = accs + (size_t)NB * D_DIM;     // 2*NB floats (m then l)

    fused_pass_kernel<<<NB, TPB, 0, stream>>>(x, P, accs, mlvals);
    combine_kernel<<<D_DIM / 64, 256, 0, stream>>>(accs, mlvals, out);
}

// Round 4
// 205.501 us; speedup vs baseline: 7.1377x; 2.1379x over previous
//
#include <hip/hip_runtime.h>
#include <math.h>

#define N_PAT 16384
#define D_DIM 16384
#define NB    256                 // fused-pass blocks: exactly 1 per CU
#define TPB   1024                // 16 waves
#define ROWS  (N_PAT / NB)        // 64 rows per block
#define VPT   (D_DIM / (TPB * 4)) // 4 float4 per thread
#define NWAVE (TPB / 64)          // 16 waves
#define EPSV  1e-8f

// Fused single pass over P (round-1 structure: the one shape the allocator
// handles without spilling — ~50 data VGPRs, single row buffer, plain
// __syncthreads). Per row: dot/ssq wave-shfl + one-barrier LDS block reduce
// (parity slots), then online-softmax update of register-resident partial.
__global__ __launch_bounds__(TPB, 4) void fused_pass_kernel(
    const float* __restrict__ x, const float* __restrict__ P,
    float* __restrict__ accs, float* __restrict__ mlvals)
{
    __shared__ float2 red[2][NWAVE];   // parity slots -> 1 barrier per row
    const int t = threadIdx.x;
    const int b = blockIdx.x;
    const int lane = t & 63;
    const int wid = t >> 6;
    const float4* __restrict__ x4 = (const float4*)x;
    const float4* __restrict__ P4 = (const float4*)P;

    float4 xv[VPT], acc[VPT], v[VPT];
    float xss = 0.f;
#pragma unroll
    for (int j = 0; j < VPT; ++j) {
        xv[j] = x4[t + TPB * j];
        acc[j] = make_float4(0.f, 0.f, 0.f, 0.f);
        xss += xv[j].x * xv[j].x + xv[j].y * xv[j].y
             + xv[j].z * xv[j].z + xv[j].w * xv[j].w;
    }
#pragma unroll
    for (int o = 32; o > 0; o >>= 1) xss += __shfl_down(xss, o, 64);
    if (lane == 0) red[0][wid] = make_float2(xss, 0.f);
    __syncthreads();
    float xn = 0.f;
#pragma unroll
    for (int w = 0; w < NWAVE; ++w) xn += red[0][w].x;
    const float inv_xn = 1.f / fmaxf(sqrtf(xn), EPSV);
    __syncthreads();

    float m = -INFINITY, l = 0.f;
    for (int r = 0; r < ROWS; ++r) {
        const size_t row = (size_t)b * ROWS + r;
        const float4* __restrict__ pr = P4 + row * (size_t)(D_DIM / 4);
#pragma unroll
        for (int j = 0; j < VPT; ++j) v[j] = pr[t + TPB * j];
        float dot = 0.f, ssq = 0.f;
#pragma unroll
        for (int j = 0; j < VPT; ++j) {
            dot = fmaf(v[j].x, xv[j].x, dot); dot = fmaf(v[j].y, xv[j].y, dot);
            dot = fmaf(v[j].z, xv[j].z, dot); dot = fmaf(v[j].w, xv[j].w, dot);
            ssq = fmaf(v[j].x, v[j].x, ssq);  ssq = fmaf(v[j].y, v[j].y, ssq);
            ssq = fmaf(v[j].z, v[j].z, ssq);  ssq = fmaf(v[j].w, v[j].w, ssq);
        }
#pragma unroll
        for (int o = 32; o > 0; o >>= 1) {
            dot += __shfl_down(dot, o, 64);
            ssq += __shfl_down(ssq, o, 64);
        }
        if (lane == 0) red[r & 1][wid] = make_float2(dot, ssq);
        __syncthreads();
        dot = 0.f; ssq = 0.f;
#pragma unroll
        for (int w = 0; w < NWAVE; ++w) {
            const float2 rv = red[r & 1][w];
            dot += rv.x; ssq += rv.y;
        }
        const float s = dot * inv_xn / fmaxf(sqrtf(ssq), EPSV);
        if (s > m) {                    // block-uniform branch
            const float sc = __expf(m - s);   // exp(-inf)=0 on first row
            l = fmaf(l, sc, 1.f);
#pragma unroll
            for (int j = 0; j < VPT; ++j) {
                acc[j].x = fmaf(acc[j].x, sc, v[j].x);
                acc[j].y = fmaf(acc[j].y, sc, v[j].y);
                acc[j].z = fmaf(acc[j].z, sc, v[j].z);
                acc[j].w = fmaf(acc[j].w, sc, v[j].w);
            }
            m = s;
        } else {
            const float p = __expf(s - m);
            l += p;
#pragma unroll
            for (int j = 0; j < VPT; ++j) {
                acc[j].x = fmaf(p, v[j].x, acc[j].x);
                acc[j].y = fmaf(p, v[j].y, acc[j].y);
                acc[j].z = fmaf(p, v[j].z, acc[j].z);
                acc[j].w = fmaf(p, v[j].w, acc[j].w);
            }
        }
    }

    float4* __restrict__ oa = (float4*)(accs + (size_t)b * D_DIM);
#pragma unroll
    for (int j = 0; j < VPT; ++j) oa[t + TPB * j] = acc[j];
    if (t == 0) { mlvals[b] = m; mlvals[NB + b] = l; }
}

// Fused weights + combine: 256 blocks x 256 threads. Each block owns 64
// output d's; its 4 waves split the 256 partials (64 each) for load ILP,
// then LDS tree-reduce. Weights recomputed per block from mlvals (L2-hot).
__global__ __launch_bounds__(256) void combine_kernel(
    const float* __restrict__ accs, const float* __restrict__ mlvals,
    float* __restrict__ out)
{
    __shared__ float wsh[NB];
    __shared__ float red2[4][64];
    __shared__ float mred[4], dred[4];
    const int t = threadIdx.x;
    const int lane = t & 63;
    const int w = t >> 6;

    const float mv = mlvals[t];        // one (m,l) pair per thread
    const float lv = mlvals[NB + t];
    float mm = mv;
#pragma unroll
    for (int o = 32; o > 0; o >>= 1) mm = fmaxf(mm, __shfl_down(mm, o, 64));
    if (lane == 0) mred[w] = mm;
    __syncthreads();
    const float M = fmaxf(fmaxf(mred[0], mred[1]), fmaxf(mred[2], mred[3]));
    const float e = __expf(mv - M);
    float c = lv * e;
#pragma unroll
    for (int o = 32; o > 0; o >>= 1) c += __shfl_down(c, o, 64);
    if (lane == 0) dred[w] = c;
    __syncthreads();
    const float denom = dred[0] + dred[1] + dred[2] + dred[3];
    wsh[t] = e / (denom * (float)N_PAT);
    __syncthreads();

    const int d = blockIdx.x * 64 + lane;
    float s = 0.f;
#pragma unroll 8
    for (int bb = w * (NB / 4); bb < (w + 1) * (NB / 4); ++bb)
        s = fmaf(wsh[bb], accs[(size_t)bb * D_DIM + d], s);
    red2[w][lane] = s;
    __syncthreads();
    if (w == 0)
        out[d] = red2[0][lane] + red2[1][lane] + red2[2][lane] + red2[3][lane];
}

extern "C" void kernel_launch(void* const* d_in, const int* in_sizes, int n_in,
                              void* d_out, int out_size, void* d_ws, size_t ws_size,
                              hipStream_t stream) {
    const float* x = (const float*)d_in[0];        // 128*128 f32
    const float* P = (const float*)d_in[1];        // 16384*16384 f32
    float* out = (float*)d_out;                    // 16384 f32

    float* accs   = (float*)d_ws;                  // NB * D floats = 16 MB
    float* mlvals = accs + (size_t)NB * D_DIM;     // 2*NB floats (m then l)

    fused_pass_kernel<<<NB, TPB, 0, stream>>>(x, P, accs, mlvals);
    combine_kernel<<<D_DIM / 64, 256, 0, stream>>>(accs, mlvals, out);
}